// Round 10
// baseline (1030.958 us; speedup 1.0000x reference)
//
#include <hip/hip_runtime.h>
#include <hip/hip_bf16.h>
#include <hip/hip_fp16.h>

typedef _Float16 half8 __attribute__((ext_vector_type(8)));
typedef _Float16 h2    __attribute__((ext_vector_type(2)));
typedef float    f32x4 __attribute__((ext_vector_type(4)));

// ---------------- graph prep ----------------

__global__ void count2_k(const int* __restrict__ col, unsigned int* __restrict__ deg,
                         const int* __restrict__ batch, unsigned int* __restrict__ cnt,
                         int E, int N) {
    int e = blockIdx.x * blockDim.x + threadIdx.x;
    if (e < E) atomicAdd(&deg[col[e]], 1u);
    if (e < N) atomicAdd(&cnt[batch[e]], 1u);
}

// exclusive scan of deg -> row_ptr partials; also emits dis = rsqrt(deg+1)
__global__ void scan1_k(const unsigned int* __restrict__ deg,
                        int* __restrict__ out, int* __restrict__ bsum,
                        float* __restrict__ dis, int N) {
    __shared__ int lds[256];
    int t = threadIdx.x;
    int base = blockIdx.x * 1024 + t * 4;
    int v0 = (base + 0 < N) ? (int)deg[base + 0] : 0;
    int v1 = (base + 1 < N) ? (int)deg[base + 1] : 0;
    int v2 = (base + 2 < N) ? (int)deg[base + 2] : 0;
    int v3 = (base + 3 < N) ? (int)deg[base + 3] : 0;
    if (base + 0 < N) dis[base + 0] = rsqrtf((float)(v0 + 1));
    if (base + 1 < N) dis[base + 1] = rsqrtf((float)(v1 + 1));
    if (base + 2 < N) dis[base + 2] = rsqrtf((float)(v2 + 1));
    if (base + 3 < N) dis[base + 3] = rsqrtf((float)(v3 + 1));
    lds[t] = v0 + v1 + v2 + v3;
    __syncthreads();
    for (int off = 1; off < 256; off <<= 1) {
        int x = lds[t];
        int y = (t >= off) ? lds[t - off] : 0;
        __syncthreads();
        lds[t] = x + y;
        __syncthreads();
    }
    int excl = (t == 0) ? 0 : lds[t - 1];
    if (base + 0 < N) out[base + 0] = excl;
    excl += v0;
    if (base + 1 < N) out[base + 1] = excl;
    excl += v1;
    if (base + 2 < N) out[base + 2] = excl;
    excl += v2;
    if (base + 3 < N) out[base + 3] = excl;
    if (t == 255) bsum[blockIdx.x] = lds[255];
}

__global__ void scan2_k(const int* __restrict__ bsum, int* __restrict__ boff, int nb) {
    __shared__ int lds[256];
    int t = threadIdx.x;
    lds[t] = (t < nb) ? bsum[t] : 0;
    __syncthreads();
    for (int off = 1; off < 256; off <<= 1) {
        int x = lds[t];
        int y = (t >= off) ? lds[t - off] : 0;
        __syncthreads();
        lds[t] = x + y;
        __syncthreads();
    }
    boff[t] = (t == 0) ? 0 : lds[t - 1];
}

__global__ void scan3_k(int* __restrict__ row_ptr, int* __restrict__ cursor,
                        const int* __restrict__ boff, int N, int E) {
    int i = blockIdx.x * blockDim.x + threadIdx.x;
    if (i < N) {
        int v = row_ptr[i] + boff[i >> 10];
        row_ptr[i] = v;
        cursor[i]  = v;
    }
    if (i == N) row_ptr[N] = E;
}

__global__ void fill_k(const int* __restrict__ row,
                       const int* __restrict__ col,
                       int* __restrict__ cursor, int* __restrict__ csr_row, int E) {
    int e = blockIdx.x * blockDim.x + threadIdx.x;
    if (e < E) {
        int c = col[e];
        int p = atomicAdd(&cursor[c], 1);
        __builtin_nontemporal_store(row[e], &csr_row[p]);  // scatter: bypass L2
    }
}

// all four W[k][n] f32 -> Wt[w][n][k] f16 (transposed), one launch
__global__ void wtcast4_k(const float* __restrict__ W1, const float* __restrict__ W2,
                          const float* __restrict__ W3, const float* __restrict__ W4,
                          _Float16* __restrict__ Wt) {
    int t = blockIdx.x * 256 + threadIdx.x;  // 65536
    int w = t >> 14, idx = t & 16383;
    int k = idx >> 7, n = idx & 127;
    const float* W = (w == 0) ? W1 : (w == 1) ? W2 : (w == 2) ? W3 : W4;
    Wt[(size_t)w * 16384 + n * 128 + k] = (_Float16)W[idx];
}

// ---------------- MFMA GEMM: H[r][:] = dis[r] * (A[r][:] @ W), fp16 out ----------
// block = 256 threads (4 waves), 128 rows/block, wave = 32 rows (2 m-tiles).
// No LDS: A-frags direct (coalesced), Wt-frags from L2.
// mfma_f32_16x16x32_f16: A row=l&15,k=(l>>4)*8+j ; B col=l&15 (Wt[n][k] contiguous);
// D col=l&15, row=(l>>4)*4+r.
template<bool F32IN>
__global__ __launch_bounds__(256) void gemm_mfma_k(const void* __restrict__ Ain,
                                                   const _Float16* __restrict__ Wt,
                                                   const float* __restrict__ dis,
                                                   _Float16* __restrict__ H, int N) {
    int wave = threadIdx.x >> 6, l = threadIdx.x & 63;
    int lr = l & 15, lk = l >> 4;
    int row0 = blockIdx.x * 128 + wave * 32;

    half8 a[2][4];
#pragma unroll
    for (int m = 0; m < 2; ++m) {
#pragma unroll
        for (int s = 0; s < 4; ++s) {
            int r = row0 + m * 16 + lr;
            int k0 = s * 32 + lk * 8;
            half8 t;
            if (r < N) {
                if constexpr (F32IN) {
                    const float* ap = (const float*)Ain + (size_t)r * 128 + k0;
                    float4 u0 = *(const float4*)ap;
                    float4 u1 = *(const float4*)(ap + 4);
                    t[0] = (_Float16)u0.x; t[1] = (_Float16)u0.y;
                    t[2] = (_Float16)u0.z; t[3] = (_Float16)u0.w;
                    t[4] = (_Float16)u1.x; t[5] = (_Float16)u1.y;
                    t[6] = (_Float16)u1.z; t[7] = (_Float16)u1.w;
                } else {
                    t = *(const half8*)((const _Float16*)Ain + (size_t)r * 128 + k0);
                }
            } else {
#pragma unroll
                for (int i = 0; i < 8; ++i) t[i] = (_Float16)0.0f;
            }
            a[m][s] = t;
        }
    }

    f32x4 acc[2][8];
#pragma unroll
    for (int m = 0; m < 2; ++m)
#pragma unroll
        for (int nt = 0; nt < 8; ++nt)
#pragma unroll
            for (int r = 0; r < 4; ++r) acc[m][nt][r] = 0.0f;

#pragma unroll
    for (int nt = 0; nt < 8; ++nt) {
        half8 b[4];
#pragma unroll
        for (int s = 0; s < 4; ++s)
            b[s] = *(const half8*)(Wt + (size_t)(nt * 16 + lr) * 128 + s * 32 + lk * 8);
#pragma unroll
        for (int m = 0; m < 2; ++m)
#pragma unroll
            for (int s = 0; s < 4; ++s)
                acc[m][nt] = __builtin_amdgcn_mfma_f32_16x16x32_f16(a[m][s], b[s],
                                                                    acc[m][nt], 0, 0, 0);
    }

#pragma unroll
    for (int m = 0; m < 2; ++m) {
        int   orow[4];
        float dv[4];
#pragma unroll
        for (int r = 0; r < 4; ++r) {
            orow[r] = row0 + m * 16 + lk * 4 + r;
            dv[r]   = (orow[r] < N) ? dis[orow[r]] : 0.0f;
        }
#pragma unroll
        for (int nt = 0; nt < 8; ++nt)
#pragma unroll
            for (int r = 0; r < 4; ++r)
                if (orow[r] < N)
                    H[(size_t)orow[r] * 128 + nt * 16 + lr] =
                        (_Float16)(acc[m][nt][r] * dv[r]);
    }
}

// ---------------- aggregation, 16B/lane gather ----------------
// wave = 4 groups x 16 lanes. Group a reads neighbor row s_{j+a}; lane covers
// features [8b, 8b+8). One VMEM instr = 4 neighbors (1KB). Cross-group feature
// sum via 2x shfl_xor. out = relu(di*(sum h'[nbr] + h'[self]) + bias).
template<bool POOL>
__global__ __launch_bounds__(256) void agg4_k(const _Float16* __restrict__ Hd,
                                              const int* __restrict__ row_ptr,
                                              const int* __restrict__ csr_row,
                                              const float* __restrict__ dis,
                                              const float* __restrict__ bias,
                                              _Float16* __restrict__ Hout,
                                              const int* __restrict__ batch,
                                              float* __restrict__ pout, int N) {
    int wid  = (int)((blockIdx.x * (size_t)blockDim.x + threadIdx.x) >> 6);
    int lane = threadIdx.x & 63;
    if (wid >= N) return;
    int a = lane >> 4, b = lane & 15;
    const _Float16* hp = Hd + b * 8;   // this lane's 8-feature slice

    float acc[8];
    if (a == 0) {   // self term handled by group 0
        half8 s = *(const half8*)(hp + (size_t)wid * 128);
#pragma unroll
        for (int f = 0; f < 8; ++f) acc[f] = (float)s[f];
    } else {
#pragma unroll
        for (int f = 0; f < 8; ++f) acc[f] = 0.0f;
    }

    int beg = row_ptr[wid], end = row_ptr[wid + 1];
    int j = beg;
    for (; j + 8 <= end; j += 8) {      // 8 neighbors per iter (2 per group)
        int s0 = csr_row[j + a];
        int s1 = csr_row[j + 4 + a];
        half8 v0 = *(const half8*)(hp + (size_t)s0 * 128);
        half8 v1 = *(const half8*)(hp + (size_t)s1 * 128);
#pragma unroll
        for (int f = 0; f < 8; ++f) acc[f] += (float)v0[f] + (float)v1[f];
    }
    for (; j < end; j += 4) {           // tail: up to 2 predicated steps
        int idx = j + a;
        if (idx < end) {
            int s = csr_row[idx];
            half8 v = *(const half8*)(hp + (size_t)s * 128);
#pragma unroll
            for (int f = 0; f < 8; ++f) acc[f] += (float)v[f];
        }
    }

    // cross-group reduce: lanes {b, b+16, b+32, b+48} hold partial feature sums
#pragma unroll
    for (int f = 0; f < 8; ++f) {
        acc[f] += __shfl_xor(acc[f], 16, 64);
        acc[f] += __shfl_xor(acc[f], 32, 64);
    }

    if (a == 0) {
        float di = dis[wid];
        float o[8];
#pragma unroll
        for (int f = 0; f < 8; ++f)
            o[f] = fmaxf(fmaf(di, acc[f], bias[b * 8 + f]), 0.0f);
        if constexpr (POOL) {
            int g = batch[wid];
#pragma unroll
            for (int f = 0; f < 8; ++f)
                atomicAdd(&pout[(size_t)g * 128 + b * 8 + f], o[f]);
        } else {
            half8 ov;
#pragma unroll
            for (int f = 0; f < 8; ++f) ov[f] = (_Float16)o[f];
            *(half8*)(Hout + (size_t)wid * 128 + b * 8) = ov;
        }
    }
}

__global__ void fin_k(float* __restrict__ out, const unsigned int* __restrict__ cnt,
                      int total) {
    int i = blockIdx.x * blockDim.x + threadIdx.x;
    if (i < total) out[i] = out[i] / fmaxf((float)cnt[i >> 7], 1.0f);
}

// ---------------- launch ----------------
extern "C" void kernel_launch(void* const* d_in, const int* in_sizes, int n_in,
                              void* d_out, int out_size, void* d_ws, size_t ws_size,
                              hipStream_t stream) {
    const float* x  = (const float*)d_in[0];
    const float* W1 = (const float*)d_in[1]; const float* b1 = (const float*)d_in[2];
    const float* W2 = (const float*)d_in[3]; const float* b2 = (const float*)d_in[4];
    const float* W3 = (const float*)d_in[5]; const float* b3 = (const float*)d_in[6];
    const float* W4 = (const float*)d_in[7]; const float* b4 = (const float*)d_in[8];
    const int* eidx  = (const int*)d_in[9];
    const int* batch = (const int*)d_in[10];

    int N = in_sizes[0] / 128;
    int E = in_sizes[9] / 2;
    const int* erow = eidx;      // source
    const int* ecol = eidx + E;  // target

    char* ws = (char*)d_ws;
    size_t off = 0;
    auto alloc = [&](size_t bytes) -> void* {
        void* p = ws + off;
        off = (off + bytes + 255) & ~(size_t)255;
        return p;
    };
    unsigned int* deg    = (unsigned int*)alloc((size_t)N * 4);
    float*        dis    = (float*)alloc((size_t)N * 4);
    int*          rowp   = (int*)alloc((size_t)(N + 1) * 4);
    int*          cursor = (int*)alloc((size_t)N * 4);
    int*          bsum   = (int*)alloc(1024);
    int*          boff   = (int*)alloc(1024);
    unsigned int* cnt    = (unsigned int*)alloc(2048 * 4);
    int*          csr    = (int*)alloc((size_t)E * 4);
    _Float16*     Wt     = (_Float16*)alloc(4 * 128 * 128 * 2);
    _Float16*     hA     = (_Float16*)alloc((size_t)N * 128 * 2);
    _Float16*     hB     = (_Float16*)alloc((size_t)N * 128 * 2);
    (void)ws_size;

    hipMemsetAsync(deg, 0, (size_t)N * 4, stream);
    hipMemsetAsync(cnt, 0, 2048 * 4, stream);
    hipMemsetAsync(d_out, 0, (size_t)out_size * 4, stream);

    const int B = 256;
    count2_k<<<(E + B - 1) / B, B, 0, stream>>>(ecol, deg, batch, cnt, E, N);
    int nb = (N + 1023) / 1024;
    scan1_k<<<nb, 256, 0, stream>>>(deg, rowp, bsum, dis, N);
    scan2_k<<<1, 256, 0, stream>>>(bsum, boff, nb);
    scan3_k<<<(N + 1 + B - 1) / B, B, 0, stream>>>(rowp, cursor, boff, N, E);
    fill_k<<<(E + B - 1) / B, B, 0, stream>>>(erow, ecol, cursor, csr, E);
    wtcast4_k<<<256, 256, 0, stream>>>(W1, W2, W3, W4, Wt);

    int gb = (N + 127) / 128;  // gemm blocks
    int ab = (N + 3) / 4;      // agg: 4 waves (nodes) per block

    gemm_mfma_k<true ><<<gb, 256, 0, stream>>>(x, Wt, dis, hA, N);
    agg4_k<false><<<ab, 256, 0, stream>>>(hA, rowp, csr, dis, b1, hB, batch, nullptr, N);
    gemm_mfma_k<false><<<gb, 256, 0, stream>>>(hB, Wt + 16384, dis, hA, N);
    agg4_k<false><<<ab, 256, 0, stream>>>(hA, rowp, csr, dis, b2, hB, batch, nullptr, N);
    gemm_mfma_k<false><<<gb, 256, 0, stream>>>(hB, Wt + 32768, dis, hA, N);
    agg4_k<false><<<ab, 256, 0, stream>>>(hA, rowp, csr, dis, b3, hB, batch, nullptr, N);
    gemm_mfma_k<false><<<gb, 256, 0, stream>>>(hB, Wt + 49152, dis, hA, N);
    agg4_k<true ><<<ab, 256, 0, stream>>>(hA, rowp, csr, dis, b4, nullptr, batch,
                                          (float*)d_out, N);

    fin_k<<<(out_size + B - 1) / B, B, 0, stream>>>((float*)d_out, cnt, out_size);
}

// Round 11
// 726.201 us; speedup vs baseline: 1.4197x; 1.4197x over previous
//
#include <hip/hip_runtime.h>
#include <hip/hip_bf16.h>
#include <hip/hip_fp16.h>

typedef _Float16 half8 __attribute__((ext_vector_type(8)));
typedef _Float16 h2    __attribute__((ext_vector_type(2)));
typedef float    f32x4 __attribute__((ext_vector_type(4)));

// ---------------- graph prep ----------------

__global__ void count2_k(const int* __restrict__ col, unsigned int* __restrict__ deg,
                         const int* __restrict__ batch, unsigned int* __restrict__ cnt,
                         int E, int N) {
    int e = blockIdx.x * blockDim.x + threadIdx.x;
    if (e < E) atomicAdd(&deg[col[e]], 1u);
    if (e < N) atomicAdd(&cnt[batch[e]], 1u);
}

// exclusive scan of deg -> row_ptr partials; also emits dis = rsqrt(deg+1)
__global__ void scan1_k(const unsigned int* __restrict__ deg,
                        int* __restrict__ out, int* __restrict__ bsum,
                        float* __restrict__ dis, int N) {
    __shared__ int lds[256];
    int t = threadIdx.x;
    int base = blockIdx.x * 1024 + t * 4;
    int v0 = (base + 0 < N) ? (int)deg[base + 0] : 0;
    int v1 = (base + 1 < N) ? (int)deg[base + 1] : 0;
    int v2 = (base + 2 < N) ? (int)deg[base + 2] : 0;
    int v3 = (base + 3 < N) ? (int)deg[base + 3] : 0;
    if (base + 0 < N) dis[base + 0] = rsqrtf((float)(v0 + 1));
    if (base + 1 < N) dis[base + 1] = rsqrtf((float)(v1 + 1));
    if (base + 2 < N) dis[base + 2] = rsqrtf((float)(v2 + 1));
    if (base + 3 < N) dis[base + 3] = rsqrtf((float)(v3 + 1));
    lds[t] = v0 + v1 + v2 + v3;
    __syncthreads();
    for (int off = 1; off < 256; off <<= 1) {
        int x = lds[t];
        int y = (t >= off) ? lds[t - off] : 0;
        __syncthreads();
        lds[t] = x + y;
        __syncthreads();
    }
    int excl = (t == 0) ? 0 : lds[t - 1];
    if (base + 0 < N) out[base + 0] = excl;
    excl += v0;
    if (base + 1 < N) out[base + 1] = excl;
    excl += v1;
    if (base + 2 < N) out[base + 2] = excl;
    excl += v2;
    if (base + 3 < N) out[base + 3] = excl;
    if (t == 255) bsum[blockIdx.x] = lds[255];
}

__global__ void scan2_k(const int* __restrict__ bsum, int* __restrict__ boff, int nb) {
    __shared__ int lds[256];
    int t = threadIdx.x;
    lds[t] = (t < nb) ? bsum[t] : 0;
    __syncthreads();
    for (int off = 1; off < 256; off <<= 1) {
        int x = lds[t];
        int y = (t >= off) ? lds[t - off] : 0;
        __syncthreads();
        lds[t] = x + y;
        __syncthreads();
    }
    boff[t] = (t == 0) ? 0 : lds[t - 1];
}

__global__ void scan3_k(int* __restrict__ row_ptr, int* __restrict__ cursor,
                        const int* __restrict__ boff, int N, int E) {
    int i = blockIdx.x * blockDim.x + threadIdx.x;
    if (i < N) {
        int v = row_ptr[i] + boff[i >> 10];
        row_ptr[i] = v;
        cursor[i]  = v;
    }
    if (i == N) row_ptr[N] = E;
}

// exclusive scan of per-graph counts (G=2048) -> goff[G]+sentinel, one block
__global__ void gscan_k(const unsigned int* __restrict__ cnt, int* __restrict__ goff,
                        int G, int N) {
    __shared__ int lds[256];
    int t = threadIdx.x;
    int base = t * 8;
    int v[8];
    int s = 0;
#pragma unroll
    for (int i = 0; i < 8; ++i) {
        v[i] = (base + i < G) ? (int)cnt[base + i] : 0;
        s += v[i];
    }
    lds[t] = s;
    __syncthreads();
    for (int off = 1; off < 256; off <<= 1) {
        int x = lds[t];
        int y = (t >= off) ? lds[t - off] : 0;
        __syncthreads();
        lds[t] = x + y;
        __syncthreads();
    }
    int excl = (t == 0) ? 0 : lds[t - 1];
#pragma unroll
    for (int i = 0; i < 8; ++i) {
        if (base + i < G) goff[base + i] = excl;
        excl += v[i];
    }
    if (t == 255) goff[G] = N;
}

__global__ void fill_k(const int* __restrict__ row,
                       const int* __restrict__ col,
                       int* __restrict__ cursor, int* __restrict__ csr_row, int E) {
    int e = blockIdx.x * blockDim.x + threadIdx.x;
    if (e < E) {
        int c = col[e];
        int p = atomicAdd(&cursor[c], 1);
        __builtin_nontemporal_store(row[e], &csr_row[p]);  // scatter: bypass L2
    }
}

// all four W[k][n] f32 -> Wt[w][n][k] f16 (transposed), one launch
__global__ void wtcast4_k(const float* __restrict__ W1, const float* __restrict__ W2,
                          const float* __restrict__ W3, const float* __restrict__ W4,
                          _Float16* __restrict__ Wt) {
    int t = blockIdx.x * 256 + threadIdx.x;  // 65536
    int w = t >> 14, idx = t & 16383;
    int k = idx >> 7, n = idx & 127;
    const float* W = (w == 0) ? W1 : (w == 1) ? W2 : (w == 2) ? W3 : W4;
    Wt[(size_t)w * 16384 + n * 128 + k] = (_Float16)W[idx];
}

// ---------------- MFMA GEMM: H[r][:] = dis[r] * (A[r][:] @ W), fp16 out ----------
// block = 256 threads (4 waves), 128 rows/block, wave = 32 rows (2 m-tiles).
// No LDS: A-frags direct (coalesced), Wt-frags from L2.
// mfma_f32_16x16x32_f16: A row=l&15,k=(l>>4)*8+j ; B col=l&15 (Wt[n][k] contiguous);
// D col=l&15, row=(l>>4)*4+r.
template<bool F32IN>
__global__ __launch_bounds__(256) void gemm_mfma_k(const void* __restrict__ Ain,
                                                   const _Float16* __restrict__ Wt,
                                                   const float* __restrict__ dis,
                                                   _Float16* __restrict__ H, int N) {
    int wave = threadIdx.x >> 6, l = threadIdx.x & 63;
    int lr = l & 15, lk = l >> 4;
    int row0 = blockIdx.x * 128 + wave * 32;

    half8 a[2][4];
#pragma unroll
    for (int m = 0; m < 2; ++m) {
#pragma unroll
        for (int s = 0; s < 4; ++s) {
            int r = row0 + m * 16 + lr;
            int k0 = s * 32 + lk * 8;
            half8 t;
            if (r < N) {
                if constexpr (F32IN) {
                    const float* ap = (const float*)Ain + (size_t)r * 128 + k0;
                    float4 u0 = *(const float4*)ap;
                    float4 u1 = *(const float4*)(ap + 4);
                    t[0] = (_Float16)u0.x; t[1] = (_Float16)u0.y;
                    t[2] = (_Float16)u0.z; t[3] = (_Float16)u0.w;
                    t[4] = (_Float16)u1.x; t[5] = (_Float16)u1.y;
                    t[6] = (_Float16)u1.z; t[7] = (_Float16)u1.w;
                } else {
                    t = *(const half8*)((const _Float16*)Ain + (size_t)r * 128 + k0);
                }
            } else {
#pragma unroll
                for (int i = 0; i < 8; ++i) t[i] = (_Float16)0.0f;
            }
            a[m][s] = t;
        }
    }

    f32x4 acc[2][8];
#pragma unroll
    for (int m = 0; m < 2; ++m)
#pragma unroll
        for (int nt = 0; nt < 8; ++nt)
#pragma unroll
            for (int r = 0; r < 4; ++r) acc[m][nt][r] = 0.0f;

#pragma unroll
    for (int nt = 0; nt < 8; ++nt) {
        half8 b[4];
#pragma unroll
        for (int s = 0; s < 4; ++s)
            b[s] = *(const half8*)(Wt + (size_t)(nt * 16 + lr) * 128 + s * 32 + lk * 8);
#pragma unroll
        for (int m = 0; m < 2; ++m)
#pragma unroll
            for (int s = 0; s < 4; ++s)
                acc[m][nt] = __builtin_amdgcn_mfma_f32_16x16x32_f16(a[m][s], b[s],
                                                                    acc[m][nt], 0, 0, 0);
    }

#pragma unroll
    for (int m = 0; m < 2; ++m) {
        int   orow[4];
        float dv[4];
#pragma unroll
        for (int r = 0; r < 4; ++r) {
            orow[r] = row0 + m * 16 + lk * 4 + r;
            dv[r]   = (orow[r] < N) ? dis[orow[r]] : 0.0f;
        }
#pragma unroll
        for (int nt = 0; nt < 8; ++nt)
#pragma unroll
            for (int r = 0; r < 4; ++r)
                if (orow[r] < N)
                    H[(size_t)orow[r] * 128 + nt * 16 + lr] =
                        (_Float16)(acc[m][nt][r] * dv[r]);
    }
}

// ---------------- aggregation, 16B/lane gather ----------------
// wave = 4 groups x 16 lanes. Group a reads neighbor row s_{j+a}; lane covers
// features [8b, 8b+8). One VMEM instr = 4 neighbors (1KB). Cross-group feature
// sum via 2x shfl_xor. out = relu(di*(sum h'[nbr] + h'[self]) + bias).
__global__ __launch_bounds__(256) void agg4_k(const _Float16* __restrict__ Hd,
                                              const int* __restrict__ row_ptr,
                                              const int* __restrict__ csr_row,
                                              const float* __restrict__ dis,
                                              const float* __restrict__ bias,
                                              _Float16* __restrict__ Hout, int N) {
    int wid  = (int)((blockIdx.x * (size_t)blockDim.x + threadIdx.x) >> 6);
    int lane = threadIdx.x & 63;
    if (wid >= N) return;
    int a = lane >> 4, b = lane & 15;
    const _Float16* hp = Hd + b * 8;   // this lane's 8-feature slice

    float acc[8];
    if (a == 0) {   // self term handled by group 0
        half8 s = *(const half8*)(hp + (size_t)wid * 128);
#pragma unroll
        for (int f = 0; f < 8; ++f) acc[f] = (float)s[f];
    } else {
#pragma unroll
        for (int f = 0; f < 8; ++f) acc[f] = 0.0f;
    }

    int beg = row_ptr[wid], end = row_ptr[wid + 1];
    int j = beg;
    for (; j + 8 <= end; j += 8) {      // 8 neighbors per iter (2 per group)
        int s0 = csr_row[j + a];
        int s1 = csr_row[j + 4 + a];
        half8 v0 = *(const half8*)(hp + (size_t)s0 * 128);
        half8 v1 = *(const half8*)(hp + (size_t)s1 * 128);
#pragma unroll
        for (int f = 0; f < 8; ++f) acc[f] += (float)v0[f] + (float)v1[f];
    }
    for (; j < end; j += 4) {           // tail: up to 2 predicated steps
        int idx = j + a;
        if (idx < end) {
            int s = csr_row[idx];
            half8 v = *(const half8*)(hp + (size_t)s * 128);
#pragma unroll
            for (int f = 0; f < 8; ++f) acc[f] += (float)v[f];
        }
    }

    // cross-group reduce: lanes {b, b+16, b+32, b+48} hold partial feature sums
#pragma unroll
    for (int f = 0; f < 8; ++f) {
        acc[f] += __shfl_xor(acc[f], 16, 64);
        acc[f] += __shfl_xor(acc[f], 32, 64);
    }

    if (a == 0) {
        float di = dis[wid];
        half8 ov;
#pragma unroll
        for (int f = 0; f < 8; ++f)
            ov[f] = (_Float16)fmaxf(fmaf(di, acc[f], bias[b * 8 + f]), 0.0f);
        *(half8*)(Hout + (size_t)wid * 128 + b * 8) = ov;
    }
}

// ---------------- segmented mean-pool over sorted batch (no atomics) ----------
// one wave per graph; lane = 2 features; serial loop over the graph's node rows
__global__ __launch_bounds__(256) void pool_seg_k(const _Float16* __restrict__ Hd,
                                                  const int* __restrict__ goff,
                                                  float* __restrict__ out, int G) {
    int g    = (int)((blockIdx.x * (size_t)blockDim.x + threadIdx.x) >> 6);
    int lane = threadIdx.x & 63;
    if (g >= G) return;
    int beg = goff[g], end = goff[g + 1];
    const _Float16* hp = Hd + lane * 2;
    float sx = 0.0f, sy = 0.0f;
    for (int n = beg; n < end; ++n) {
        h2 v = *(const h2*)(hp + (size_t)n * 128);
        sx += (float)v[0];
        sy += (float)v[1];
    }
    float inv = 1.0f / fmaxf((float)(end - beg), 1.0f);
    float2 o = make_float2(sx * inv, sy * inv);
    *(float2*)(out + (size_t)g * 128 + lane * 2) = o;
}

// ---------------- launch ----------------
extern "C" void kernel_launch(void* const* d_in, const int* in_sizes, int n_in,
                              void* d_out, int out_size, void* d_ws, size_t ws_size,
                              hipStream_t stream) {
    const float* x  = (const float*)d_in[0];
    const float* W1 = (const float*)d_in[1]; const float* b1 = (const float*)d_in[2];
    const float* W2 = (const float*)d_in[3]; const float* b2 = (const float*)d_in[4];
    const float* W3 = (const float*)d_in[5]; const float* b3 = (const float*)d_in[6];
    const float* W4 = (const float*)d_in[7]; const float* b4 = (const float*)d_in[8];
    const int* eidx  = (const int*)d_in[9];
    const int* batch = (const int*)d_in[10];

    int N = in_sizes[0] / 128;
    int E = in_sizes[9] / 2;
    const int G = 2048;
    const int* erow = eidx;      // source
    const int* ecol = eidx + E;  // target

    char* ws = (char*)d_ws;
    size_t off = 0;
    auto alloc = [&](size_t bytes) -> void* {
        void* p = ws + off;
        off = (off + bytes + 255) & ~(size_t)255;
        return p;
    };
    unsigned int* deg    = (unsigned int*)alloc((size_t)N * 4);
    float*        dis    = (float*)alloc((size_t)N * 4);
    int*          rowp   = (int*)alloc((size_t)(N + 1) * 4);
    int*          cursor = (int*)alloc((size_t)N * 4);
    int*          bsum   = (int*)alloc(1024);
    int*          boff   = (int*)alloc(1024);
    unsigned int* cnt    = (unsigned int*)alloc((size_t)G * 4);
    int*          goff   = (int*)alloc((size_t)(G + 1) * 4);
    int*          csr    = (int*)alloc((size_t)E * 4);
    _Float16*     Wt     = (_Float16*)alloc(4 * 128 * 128 * 2);
    _Float16*     hA     = (_Float16*)alloc((size_t)N * 128 * 2);
    _Float16*     hB     = (_Float16*)alloc((size_t)N * 128 * 2);
    (void)ws_size;

    hipMemsetAsync(deg, 0, (size_t)N * 4, stream);
    hipMemsetAsync(cnt, 0, (size_t)G * 4, stream);

    const int B = 256;
    count2_k<<<(E + B - 1) / B, B, 0, stream>>>(ecol, deg, batch, cnt, E, N);
    int nb = (N + 1023) / 1024;
    scan1_k<<<nb, 256, 0, stream>>>(deg, rowp, bsum, dis, N);
    scan2_k<<<1, 256, 0, stream>>>(bsum, boff, nb);
    scan3_k<<<(N + 1 + B - 1) / B, B, 0, stream>>>(rowp, cursor, boff, N, E);
    fill_k<<<(E + B - 1) / B, B, 0, stream>>>(erow, ecol, cursor, csr, E);
    gscan_k<<<1, 256, 0, stream>>>(cnt, goff, G, N);
    wtcast4_k<<<256, 256, 0, stream>>>(W1, W2, W3, W4, Wt);

    int gb = (N + 127) / 128;  // gemm blocks
    int ab = (N + 3) / 4;      // agg: 4 waves (nodes) per block
    int pb = (G + 3) / 4;      // pool: 4 waves (graphs) per block

    gemm_mfma_k<true ><<<gb, 256, 0, stream>>>(x, Wt, dis, hA, N);
    agg4_k<<<ab, 256, 0, stream>>>(hA, rowp, csr, dis, b1, hB, N);
    gemm_mfma_k<false><<<gb, 256, 0, stream>>>(hB, Wt + 16384, dis, hA, N);
    agg4_k<<<ab, 256, 0, stream>>>(hA, rowp, csr, dis, b2, hB, N);
    gemm_mfma_k<false><<<gb, 256, 0, stream>>>(hB, Wt + 32768, dis, hA, N);
    agg4_k<<<ab, 256, 0, stream>>>(hA, rowp, csr, dis, b3, hB, N);
    gemm_mfma_k<false><<<gb, 256, 0, stream>>>(hB, Wt + 49152, dis, hA, N);
    agg4_k<<<ab, 256, 0, stream>>>(hA, rowp, csr, dis, b4, hB, N);

    pool_seg_k<<<pb, 256, 0, stream>>>(hB, goff, (float*)d_out, G);
}